// Round 3
// baseline (901.318 us; speedup 1.0000x reference)
//
#include <hip/hip_runtime.h>
#include <hip/hip_bf16.h>

typedef __hip_bfloat16 bf16;
typedef __attribute__((ext_vector_type(8))) short short8;
typedef __attribute__((ext_vector_type(4))) float floatx4;
typedef __bf16 bf16x8 __attribute__((ext_vector_type(8)));

// ---------------- workspace layout ----------------
// float offsets
#define OFF_A1 0
#define OFF_C1 64
#define OFF_A2 128
#define OFF_C2 160
#define OFF_A3 192
#define OFF_C3 224
#define OFF_LP 256
#define OFF_P1S 512
#define OFF_P1Q 66048            // P1S + 1024*64
#define OFF_P2S 131584           // P1Q + 1024*64
#define OFF_P2Q 205312           // P2S + 2304*32
#define OFF_P3S 279040           // P2Q + 2304*32
#define OFF_P3Q 426496           // P3S + 4608*32
#define FLT_END 573952           // P3Q + 4608*32

// byte offsets
#define FW2_BYTE 2295808u        // FLT_END*4
#define FW3_BYTE 2332672u
#define X1_BYTE  2351104u
#define X2_BYTE  33546240u       // + (34*7*1024*64)*2
#define X3_BYTE  97247232u       // + (36*27*1024*32)*2
#define O4_BYTE  227008512u      // + (36*55*1024*32)*2

// ---------------- d_out layout (float offsets) ----------------
#define OUT0 0
#define OUT1 153600
#define OUT2 155340
#define OUT3 2827980
#define OUT4 2858700
#define OUT5 3749580
#define OUT6 3780300
#define OUT7 3933900
#define OUT8 6606540
#define OUT9 6637260
#define OUT10 7528140

__device__ __forceinline__ float b2f(bf16 v){ return __bfloat162float(v); }
__device__ __forceinline__ bf16 f2b(float v){ return __float2bfloat16(v); }
__device__ __forceinline__ unsigned short f2bu(float v){ bf16 h = __float2bfloat16(v); return *(unsigned short*)&h; }

__device__ __forceinline__ floatx4 mfma16(short8 a, short8 b, floatx4 c){
  return __builtin_amdgcn_mfma_f32_16x16x32_bf16(__builtin_bit_cast(bf16x8, a),
                                                 __builtin_bit_cast(bf16x8, b), c, 0, 0, 0);
}

__device__ __forceinline__ unsigned int nrm2(unsigned int u, float a0, float c0, float a1, float c1){
  float x0 = __uint_as_float(u << 16);
  float x1 = __uint_as_float(u & 0xffff0000u);
  float y0 = fmaxf(fmaf(a0, x0, c0), 0.f);
  float y1 = fmaxf(fmaf(a1, x1, c1), 0.f);
  return (unsigned int)f2bu(y0) | ((unsigned int)f2bu(y1) << 16);
}

// ============ weight fragment prep ============
__global__ __launch_bounds__(256) void k_prep(const float* __restrict__ W2, const float* __restrict__ W3,
                                              unsigned short* __restrict__ fw2, unsigned short* __restrict__ fw3){
  const int t = blockIdx.x*256 + threadIdx.x;
  if (t < 2304){   // fw2: [tap9][mt2][kc2][L64][8]
    const int L = t & 63, kc = (t>>6)&1, mt = (t>>7)&1, tap = t>>8;
    const int co = mt*16 + (L&15), ci0 = kc*32 + ((L>>4)&3)*8;
    #pragma unroll
    for (int j = 0; j < 8; ++j)
      fw2[(size_t)t*8 + j] = f2bu(W2[((size_t)tap*64 + ci0 + j)*32 + co]);
  }
  if (t < 1152){   // fw3: [tap9][mt2][L64][8]
    const int L = t & 63, mt = (t>>6)&1, tap = t>>7;
    const int co = mt*16 + (L&15), ci0 = ((L>>4)&3)*8;
    #pragma unroll
    for (int j = 0; j < 8; ++j)
      fw3[(size_t)t*8 + j] = f2bu(W3[((size_t)tap*32 + ci0 + j)*32 + co]);
  }
}

// ============ deconv1: Z(B,32) -> x1 (34,7,1024,64) + partials [b][64] ============
__global__ __launch_bounds__(256) void k_dc1(const float* __restrict__ Z, const float* __restrict__ W1,
                                             bf16* __restrict__ x1, float* __restrict__ ws){
  const int b = blockIdx.x, t = threadIdx.x;
  __shared__ float zs[32];
  __shared__ float w1s[3*7*64];
  __shared__ float red[256];
  if (t < 32) zs[t] = Z[b*32 + t];
  for (int i = t; i < 1344; i += 256) w1s[i] = W1[i];
  __syncthreads();
  float lsum = 0.f, lsq = 0.f;
  for (int idx = t; idx < 15232; idx += 256){
    int co = idx & 63;
    int wo = (idx >> 6) % 7;
    int ho = idx / 448;
    int kw = 6 - wo;
    float y = 0.f;
    #pragma unroll
    for (int kh = 0; kh < 3; ++kh){
      int hi = ho + kh - 2;
      if (hi >= 0 && hi < 32) y += zs[hi] * w1s[(kh*7 + kw)*64 + co];
    }
    x1[(size_t)(idx >> 6)*65536 + (size_t)b*64 + co] = f2b(y);
    lsum += y; lsq += y*y;
  }
  red[t] = lsum; __syncthreads();
  if (t < 64) ws[OFF_P1S + b*64 + t] = red[t] + red[t+64] + red[t+128] + red[t+192];
  __syncthreads();
  red[t] = lsq; __syncthreads();
  if (t < 64) ws[OFF_P1Q + b*64 + t] = red[t] + red[t+64] + red[t+128] + red[t+192];
}

// ============ BN finalize: partials laid out [part][nch] ============
__global__ __launch_bounds__(256) void k_fin(float* __restrict__ ws, const float* __restrict__ g,
                                             const float* __restrict__ bb, int ps, int pq, int npart,
                                             int nch, float inv_n, int ao, int co, int zlp){
  const int c = blockIdx.x, t = threadIdx.x;
  __shared__ float r1[256], r2[256];
  float s = 0.f, q = 0.f;
  for (int i = t; i < npart; i += 256){ s += ws[ps + i*nch + c]; q += ws[pq + i*nch + c]; }
  r1[t] = s; r2[t] = q; __syncthreads();
  for (int off = 128; off > 0; off >>= 1){
    if (t < off){ r1[t] += r1[t+off]; r2[t] += r2[t+off]; }
    __syncthreads();
  }
  if (t == 0){
    float m  = r1[0] * inv_n;
    float v  = r2[0] * inv_n - m*m;
    float is = rsqrtf(v + 1e-5f);
    float a  = g[c] * is;
    ws[ao + c] = a;
    ws[co + c] = bb[c] - a*m;
  }
  if (zlp && c == 0 && t == 0) ws[OFF_LP] = 0.f;
}

// ============ deconv2 (MFMA): x1 (34,7,1024,64) -> x2 (36,27,1024,32) ============
// hi = ho + kh - 2; wo = 4*wi + 2 - kw
__global__ __launch_bounds__(256) void k2(const unsigned short* __restrict__ x1, const unsigned short* __restrict__ fw2,
                                          unsigned short* __restrict__ x2, float* __restrict__ ws){
  const int t = threadIdx.x;
  const int b0 = blockIdx.x*16, ho = blockIdx.y;
  __shared__ unsigned short sa[21*1024];     // staging, then reused as store buffer
  __shared__ float sa1[64], sc1[64];
  __shared__ float sred[2][4][32];
  if (t < 64){ sa1[t] = ws[OFF_A1+t]; sc1[t] = ws[OFF_C1+t]; }
  __syncthreads();
  // coalesced staging: lane walks 16B chunks fastest
  for (int c = t; c < 21*128; c += 256){
    const int p = c >> 7, g = c & 127;
    const int r = p/7, wi = p - r*7;
    const int hi = ho - 2 + r;
    const int b = g >> 3, kc = (g >> 2) & 1, j = g & 3;
    const int ci0 = kc*32 + j*8;
    uint4 v = make_uint4(0,0,0,0);
    if (hi >= 0 && hi < 34){
      v = *(const uint4*)(x1 + ((size_t)(hi*7+wi)*1024 + b0 + b)*64 + ci0);
      v.x = nrm2(v.x, sa1[ci0],   sc1[ci0],   sa1[ci0+1], sc1[ci0+1]);
      v.y = nrm2(v.y, sa1[ci0+2], sc1[ci0+2], sa1[ci0+3], sc1[ci0+3]);
      v.z = nrm2(v.z, sa1[ci0+4], sc1[ci0+4], sa1[ci0+5], sc1[ci0+5]);
      v.w = nrm2(v.w, sa1[ci0+6], sc1[ci0+6], sa1[ci0+7], sc1[ci0+7]);
    }
    *(uint4*)(sa + (size_t)p*1024 + kc*512 + (j*16 + b)*8) = v;
  }
  __syncthreads();
  const int w = t>>6, L = t&63;
  floatx4 acc[8][2];
  #pragma unroll
  for (int i = 0; i < 8; ++i){ acc[i][0] = (floatx4)0.f; acc[i][1] = (floatx4)0.f; }
  const int nwi = (w < 3) ? 2 : 1;
  for (int r = 0; r < 3; ++r){
    short8 af[3][2][2];
    #pragma unroll
    for (int kw = 0; kw < 3; ++kw)
      #pragma unroll
      for (int mt = 0; mt < 2; ++mt)
        #pragma unroll
        for (int kc = 0; kc < 2; ++kc)
          af[kw][mt][kc] = *(const short8*)(fw2 + ((((size_t)(r*3+kw)*2 + mt)*2 + kc)*64 + L)*8);
    for (int ii = 0; ii < nwi; ++ii){
      const int wi = 2*w + ii;
      const short8* bp = (const short8*)(sa + (size_t)(r*7 + wi)*1024);
      short8 bf0 = bp[L];
      short8 bf1 = bp[64 + L];
      #pragma unroll
      for (int kw = 0; kw < 3; ++kw){
        const int idx = 4*ii + 2 - kw;
        #pragma unroll
        for (int mt = 0; mt < 2; ++mt){
          acc[idx][mt] = mfma16(af[kw][mt][0], bf0, acc[idx][mt]);
          acc[idx][mt] = mfma16(af[kw][mt][1], bf1, acc[idx][mt]);
        }
      }
    }
  }
  // stats
  const int bL = L & 15, jj = (L>>4)&3;
  float ss[2][4] = {{0,0,0,0},{0,0,0,0}}, sq[2][4] = {{0,0,0,0},{0,0,0,0}};
  const int nwo = (w < 3) ? 8 : 3;
  for (int idx = 0; idx < nwo; ++idx){
    #pragma unroll
    for (int mt = 0; mt < 2; ++mt){
      floatx4 a = acc[idx][mt];
      ss[mt][0] += a.x; ss[mt][1] += a.y; ss[mt][2] += a.z; ss[mt][3] += a.w;
      sq[mt][0] += a.x*a.x; sq[mt][1] += a.y*a.y; sq[mt][2] += a.z*a.z; sq[mt][3] += a.w*a.w;
    }
  }
  #pragma unroll
  for (int mt = 0; mt < 2; ++mt)
    #pragma unroll
    for (int r2 = 0; r2 < 4; ++r2){
      float v1 = ss[mt][r2], v2 = sq[mt][r2];
      for (int d = 1; d < 16; d <<= 1){ v1 += __shfl_xor(v1, d, 64); v2 += __shfl_xor(v2, d, 64); }
      if (bL == 0){
        int cch = mt*16 + jj*4 + r2;
        sred[0][w][cch] = v1;
        sred[1][w][cch] = v2;
      }
    }
  __syncthreads();            // also guarantees all sa reads (MFMA) finished
  if (t < 64){
    const int cch = t & 31, j2 = t >> 5;
    float tot = sred[j2][0][cch] + sred[j2][1][cch] + sred[j2][2][cch] + sred[j2][3][cch];
    const int bid = blockIdx.y*64 + blockIdx.x;
    ws[(j2 ? OFF_P2Q : OFF_P2S) + bid*32 + cch] = tot;
  }
  // pack accumulators into LDS (wave-local region, padded 40 shorts per b)
  unsigned short* st = sa + w*5120;
  for (int idx = 0; idx < nwo; ++idx){
    #pragma unroll
    for (int mt = 0; mt < 2; ++mt){
      floatx4 a = acc[idx][mt];
      uint2 pk;
      pk.x = (unsigned int)f2bu(a.x) | ((unsigned int)f2bu(a.y) << 16);
      pk.y = (unsigned int)f2bu(a.z) | ((unsigned int)f2bu(a.w) << 16);
      *(uint2*)(st + idx*640 + bL*40 + mt*16 + jj*4) = pk;
    }
  }
  // coalesced store: per pixel, 64 lanes x 16B = 1KB contiguous
  const int sb = L >> 2, qq2 = L & 3;
  for (int idx = 0; idx < nwo; ++idx){
    const int wo = 8*w + idx;
    uint4 v = *(const uint4*)(st + idx*640 + sb*40 + qq2*8);
    *(uint4*)(x2 + ((size_t)(ho*27+wo)*1024 + b0 + sb)*32 + qq2*8) = v;
  }
}

// ============ deconv3 (MFMA): x2 (36,27,1024,32) -> x3 (36,55,1024,32) ============
// hi = ho + kh - 1; wo = 2*wi + 2 - kw
__global__ __launch_bounds__(256) void k3(const unsigned short* __restrict__ x2, const unsigned short* __restrict__ fw3,
                                          unsigned short* __restrict__ x3, float* __restrict__ ws){
  const int t = threadIdx.x;
  const int b0 = blockIdx.x*16, ho = blockIdx.y, z = blockIdx.z;
  const int wib = z ? 13 : 0;
  __shared__ unsigned short sa[42*512];      // staging, then store buffer
  __shared__ float sa2[32], sc2[32];
  __shared__ float sred[2][4][32];
  if (t < 32){ sa2[t] = ws[OFF_A2+t]; sc2[t] = ws[OFF_C2+t]; }
  __syncthreads();
  for (int c = t; c < 42*64; c += 256){
    const int p = c >> 6, g = c & 63;
    const int r = p/14, wi = wib + (p - r*14);
    const int hi = ho - 1 + r;
    const int b = g >> 2, j = g & 3;
    const int ci0 = j*8;
    uint4 v = make_uint4(0,0,0,0);
    if (hi >= 0 && hi < 36){
      v = *(const uint4*)(x2 + ((size_t)(hi*27+wi)*1024 + b0 + b)*32 + ci0);
      v.x = nrm2(v.x, sa2[ci0],   sc2[ci0],   sa2[ci0+1], sc2[ci0+1]);
      v.y = nrm2(v.y, sa2[ci0+2], sc2[ci0+2], sa2[ci0+3], sc2[ci0+3]);
      v.z = nrm2(v.z, sa2[ci0+4], sc2[ci0+4], sa2[ci0+5], sc2[ci0+5]);
      v.w = nrm2(v.w, sa2[ci0+6], sc2[ci0+6], sa2[ci0+7], sc2[ci0+7]);
    }
    *(uint4*)(sa + (size_t)p*512 + (j*16 + b)*8) = v;
  }
  __syncthreads();
  const int w = t>>6, L = t&63;
  const int s0 = z*28 + w*7;
  const int ns = min(7, 55 - s0);
  const int wlo = (s0 >= 2) ? ((s0 - 1) >> 1) : 0;
  const int whi = min(26, (s0 + ns - 1) >> 1);
  floatx4 acc[7][2];
  #pragma unroll
  for (int i = 0; i < 7; ++i){ acc[i][0] = (floatx4)0.f; acc[i][1] = (floatx4)0.f; }
  for (int r = 0; r < 3; ++r){
    short8 af[3][2];
    #pragma unroll
    for (int kw = 0; kw < 3; ++kw)
      #pragma unroll
      for (int mt = 0; mt < 2; ++mt)
        af[kw][mt] = *(const short8*)(fw3 + (((size_t)(r*3+kw)*2 + mt)*64 + L)*8);
    for (int wi = wlo; wi <= whi; ++wi){
      short8 bf = *(const short8*)(sa + (size_t)(r*14 + wi - wib)*512 + L*8);
      #pragma unroll
      for (int kw = 0; kw < 3; ++kw){
        const int wo = 2*wi + 2 - kw;
        if (wo >= s0 && wo < s0 + ns){
          const int idx = wo - s0;
          acc[idx][0] = mfma16(af[kw][0], bf, acc[idx][0]);
          acc[idx][1] = mfma16(af[kw][1], bf, acc[idx][1]);
        }
      }
    }
  }
  const int bL = L & 15, jj = (L>>4)&3;
  float ss[2][4] = {{0,0,0,0},{0,0,0,0}}, sq[2][4] = {{0,0,0,0},{0,0,0,0}};
  for (int idx = 0; idx < ns; ++idx){
    #pragma unroll
    for (int mt = 0; mt < 2; ++mt){
      floatx4 a = acc[idx][mt];
      ss[mt][0] += a.x; ss[mt][1] += a.y; ss[mt][2] += a.z; ss[mt][3] += a.w;
      sq[mt][0] += a.x*a.x; sq[mt][1] += a.y*a.y; sq[mt][2] += a.z*a.z; sq[mt][3] += a.w*a.w;
    }
  }
  #pragma unroll
  for (int mt = 0; mt < 2; ++mt)
    #pragma unroll
    for (int r2 = 0; r2 < 4; ++r2){
      float v1 = ss[mt][r2], v2 = sq[mt][r2];
      for (int d = 1; d < 16; d <<= 1){ v1 += __shfl_xor(v1, d, 64); v2 += __shfl_xor(v2, d, 64); }
      if (bL == 0){
        int cch = mt*16 + jj*4 + r2;
        sred[0][w][cch] = v1;
        sred[1][w][cch] = v2;
      }
    }
  __syncthreads();
  if (t < 64){
    const int cch = t & 31, j2 = t >> 5;
    float tot = sred[j2][0][cch] + sred[j2][1][cch] + sred[j2][2][cch] + sred[j2][3][cch];
    const int bid = (z*36 + blockIdx.y)*64 + blockIdx.x;
    ws[(j2 ? OFF_P3Q : OFF_P3S) + bid*32 + cch] = tot;
  }
  unsigned short* st = sa + w*4480;
  for (int idx = 0; idx < ns; ++idx){
    #pragma unroll
    for (int mt = 0; mt < 2; ++mt){
      floatx4 a = acc[idx][mt];
      uint2 pk;
      pk.x = (unsigned int)f2bu(a.x) | ((unsigned int)f2bu(a.y) << 16);
      pk.y = (unsigned int)f2bu(a.z) | ((unsigned int)f2bu(a.w) << 16);
      *(uint2*)(st + idx*640 + bL*40 + mt*16 + jj*4) = pk;
    }
  }
  const int sb = L >> 2, qq2 = L & 3;
  for (int idx = 0; idx < ns; ++idx){
    const int wo = s0 + idx;
    uint4 v = *(const uint4*)(st + idx*640 + sb*40 + qq2*8);
    *(uint4*)(x3 + ((size_t)(ho*55+wo)*1024 + b0 + sb)*32 + qq2*8) = v;
  }
}

// ============ deconv4 (VALU): x3 (36,55,1024,32) -> o4 (B,36,105) via LDS row transpose ============
__global__ __launch_bounds__(256) void k_dc4(const unsigned short* __restrict__ x3, const float* __restrict__ W4,
                                             float* __restrict__ o4, const float* __restrict__ ws){
  const int t = threadIdx.x;
  const int lb = t & 63, qg = t >> 6;
  const int b = blockIdx.x*64 + lb;
  const int h3 = blockIdx.y*3;
  __shared__ float w4s[480];
  __shared__ float a3s[32], c3s[32];
  __shared__ float rowbuf[64*109];
  if (t < 32){ a3s[t] = ws[OFF_A3+t]; c3s[t] = ws[OFF_C3+t]; }
  for (int i = t; i < 480; i += 256) w4s[i] = W4[i];
  __syncthreads();
  for (int hl = 0; hl < 3; ++hl){
    const int ho = h3 + hl;
    for (int g = qg; g < 27; g += 4){
      float out[4] = {0.f, 0.f, 0.f, 0.f};
      for (int r = 0; r < 3; ++r){
        const int hi = ho - 1 + r;
        if (hi < 0 || hi >= 36) continue;
        for (int dwi = 0; dwi < 4; ++dwi){
          const int wi = 2*g + dwi;
          if (wi >= 55) break;
          float fa[32];
          const unsigned short* px = x3 + ((size_t)(hi*55+wi)*1024 + b)*32;
          #pragma unroll
          for (int q = 0; q < 4; ++q){
            uint4 v = *(const uint4*)(px + q*8);
            unsigned int uu[4] = {v.x, v.y, v.z, v.w};
            #pragma unroll
            for (int k2i = 0; k2i < 4; ++k2i){
              int ci = q*8 + k2i*2;
              float x0 = __uint_as_float(uu[k2i] << 16);
              float x1f = __uint_as_float(uu[k2i] & 0xffff0000u);
              fa[ci]   = fmaxf(fmaf(a3s[ci],   x0,  c3s[ci]),   0.f);
              fa[ci+1] = fmaxf(fmaf(a3s[ci+1], x1f, c3s[ci+1]), 0.f);
            }
          }
          #pragma unroll
          for (int s = 0; s < 4; ++s){
            const int kw = 2*dwi - s;
            if (kw < 0 || kw >= 5) continue;
            const float* wr = &w4s[(r*5 + kw)*32];
            float a = 0.f;
            #pragma unroll
            for (int ci = 0; ci < 32; ++ci) a += fa[ci]*wr[ci];
            out[s] += a;
          }
        }
      }
      #pragma unroll
      for (int s = 0; s < 4; ++s){
        const int wo = 4*g + s;
        if (wo < 105) rowbuf[lb*109 + wo] = out[s];
      }
    }
    __syncthreads();
    // dense store: per bb, 105 contiguous floats
    for (int i = t; i < 6720; i += 256){
      const int bb = i / 105, wo = i - bb*105;
      o4[(size_t)(blockIdx.x*64 + bb)*3780 + ho*105 + wo] = rowbuf[bb*109 + wo];
    }
    __syncthreads();
  }
}

// ============ node softmax / outputs ============
__global__ __launch_bounds__(256) void k_node(const float* __restrict__ o4, float* __restrict__ dout,
                                              float* __restrict__ ws){
  const int t = threadIdx.x;
  const int tg = blockIdx.x*256 + t;
  __shared__ float red[256];
  float lp = 0.f;
  {
    int b = tg / 30, n = tg - b*30;
    const float* p = o4 + (size_t)b*3780 + n*126;
    float l[6]; float mx = -1e30f;
    #pragma unroll
    for (int j = 0; j < 6; ++j){ l[j] = p[j]; mx = fmaxf(mx, l[j]); }
    float e[6]; float s = 0.f;
    #pragma unroll
    for (int j = 0; j < 6; ++j){ e[j] = expf(l[j] - mx); s += e[j]; }
    float inv = 1.f / s;
    int am = 0; float best = e[0];
    #pragma unroll
    for (int j = 1; j < 6; ++j){ if (e[j] > best){ best = e[j]; am = j; } }
    #pragma unroll
    for (int j = 0; j < 5; ++j) dout[OUT0 + (size_t)tg*5 + j] = e[j+1]*inv;
    dout[OUT3 + tg] = 1.f - e[0]*inv;
    #pragma unroll
    for (int j = 0; j < 5; ++j) dout[OUT6 + (size_t)tg*5 + j] = (am == j+1) ? 1.f : 0.f;
    dout[OUT8 + tg] = (am != 0) ? 1.f : 0.f;
    dout[OUT5 + tg] = (float)b;
    lp = logf(best*inv + 1e-7f);
  }
  red[t] = lp; __syncthreads();
  for (int off = 128; off > 0; off >>= 1){ if (t < off) red[t] += red[t+off]; __syncthreads(); }
  if (t == 0) atomicAdd(&ws[OFF_LP], red[0]);
}

// ============ edge softmax / outputs ============
__global__ __launch_bounds__(256) void k_edge(const float* __restrict__ o4, float* __restrict__ dout,
                                              float* __restrict__ ws){
  const int t = threadIdx.x;
  const int tg = blockIdx.x*256 + t;
  __shared__ float red[256];
  float lp = 0.f;
  {
    int b = tg / 435, k = tg - b*435;
    int i = 0, rem = k;
    while (rem >= 29 - i){ rem -= 29 - i; ++i; }
    int j = i + 1 + rem;
    const float* p = o4 + (size_t)b*3780 + i*126 + 6 + j*4;
    float l0 = p[0], l1 = p[1], l2 = p[2], l3 = p[3];
    float mx = fmaxf(fmaxf(l0, l1), fmaxf(l2, l3));
    float e0 = expf(l0-mx), e1 = expf(l1-mx), e2 = expf(l2-mx), e3 = expf(l3-mx);
    float inv = 1.f / (e0 + e1 + e2 + e3);
    float pr0 = e0*inv, pr1 = e1*inv, pr2 = e2*inv, pr3 = e3*inv;
    int am = 0; float best = pr0;
    if (pr1 > best){ best = pr1; am = 1; }
    if (pr2 > best){ best = pr2; am = 2; }
    if (pr3 > best){ best = pr3; am = 3; }
    size_t e1i = (size_t)b*870 + k, e2i = e1i + 435;
    dout[OUT2 + e1i*3 + 0] = pr1; dout[OUT2 + e1i*3 + 1] = pr2; dout[OUT2 + e1i*3 + 2] = pr3;
    dout[OUT2 + e2i*3 + 0] = pr1; dout[OUT2 + e2i*3 + 1] = pr2; dout[OUT2 + e2i*3 + 2] = pr3;
    dout[OUT4 + e1i] = 1.f - pr0;  dout[OUT4 + e2i] = 1.f - pr0;
    float h1 = (am == 1) ? 1.f : 0.f, h2 = (am == 2) ? 1.f : 0.f, h3 = (am == 3) ? 1.f : 0.f;
    dout[OUT7 + e1i*3 + 0] = h1; dout[OUT7 + e1i*3 + 1] = h2; dout[OUT7 + e1i*3 + 2] = h3;
    dout[OUT7 + e2i*3 + 0] = h1; dout[OUT7 + e2i*3 + 1] = h2; dout[OUT7 + e2i*3 + 2] = h3;
    dout[OUT9 + e1i] = (am != 0) ? 1.f : 0.f;  dout[OUT9 + e2i] = (am != 0) ? 1.f : 0.f;
    if (b == 0){
      dout[OUT1 + k]        = (float)i;
      dout[OUT1 + 435 + k]  = (float)j;
      dout[OUT1 + 870 + k]  = (float)j;
      dout[OUT1 + 1305 + k] = (float)i;
    }
    lp = logf(best + 1e-7f);
  }
  red[t] = lp; __syncthreads();
  for (int off = 128; off > 0; off >>= 1){ if (t < off) red[t] += red[t+off]; __syncthreads(); }
  if (t == 0) atomicAdd(&ws[OFF_LP], red[0]);
}

__global__ void k_lp_copy(float* __restrict__ dout, const float* __restrict__ ws){
  if (threadIdx.x == 0 && blockIdx.x == 0) dout[OUT10] = ws[OFF_LP];
}

extern "C" void kernel_launch(void* const* d_in, const int* in_sizes, int n_in,
                              void* d_out, int out_size, void* d_ws, size_t ws_size,
                              hipStream_t stream) {
  const float* Z  = (const float*)d_in[0];
  const float* W1 = (const float*)d_in[1];
  const float* W2 = (const float*)d_in[2];
  const float* W3 = (const float*)d_in[3];
  const float* W4 = (const float*)d_in[4];
  const float* g1 = (const float*)d_in[5];
  const float* b1 = (const float*)d_in[6];
  const float* g2 = (const float*)d_in[7];
  const float* b2 = (const float*)d_in[8];
  const float* g3 = (const float*)d_in[9];
  const float* b3 = (const float*)d_in[10];

  float* ws  = (float*)d_ws;
  char*  wsb = (char*)d_ws;
  unsigned short* fw2 = (unsigned short*)(wsb + FW2_BYTE);
  unsigned short* fw3 = (unsigned short*)(wsb + FW3_BYTE);
  bf16*           x1  = (bf16*)(wsb + X1_BYTE);
  unsigned short* x1u = (unsigned short*)(wsb + X1_BYTE);
  unsigned short* x2u = (unsigned short*)(wsb + X2_BYTE);
  unsigned short* x3u = (unsigned short*)(wsb + X3_BYTE);
  float*          o4  = (float*)(wsb + O4_BYTE);
  float* dout = (float*)d_out;
  (void)in_sizes; (void)n_in; (void)out_size; (void)ws_size;

  k_prep<<<dim3(9), dim3(256), 0, stream>>>(W2, W3, fw2, fw3);
  k_dc1<<<dim3(1024), dim3(256), 0, stream>>>(Z, W1, x1, ws);
  k_fin<<<dim3(64), dim3(256), 0, stream>>>(ws, g1, b1, OFF_P1S, OFF_P1Q, 1024, 64,
                                            1.f/243712.f, OFF_A1, OFF_C1, 0);
  k2<<<dim3(64, 36), dim3(256), 0, stream>>>(x1u, fw2, x2u, ws);
  k_fin<<<dim3(32), dim3(256), 0, stream>>>(ws, g2, b2, OFF_P2S, OFF_P2Q, 2304, 32,
                                            1.f/995328.f, OFF_A2, OFF_C2, 0);
  k3<<<dim3(64, 36, 2), dim3(256), 0, stream>>>(x2u, fw3, x3u, ws);
  k_fin<<<dim3(32), dim3(256), 0, stream>>>(ws, g3, b3, OFF_P3S, OFF_P3Q, 4608, 32,
                                            1.f/2027520.f, OFF_A3, OFF_C3, 1);
  k_dc4<<<dim3(16, 12), dim3(256), 0, stream>>>(x3u, W4, o4, ws);
  k_node<<<dim3(120), dim3(256), 0, stream>>>(o4, dout, ws);
  k_edge<<<dim3(1740), dim3(256), 0, stream>>>(o4, dout, ws);
  k_lp_copy<<<dim3(1), dim3(64), 0, stream>>>(dout, ws);
}

// Round 5
// 507.944 us; speedup vs baseline: 1.7744x; 1.7744x over previous
//
#include <hip/hip_runtime.h>
#include <hip/hip_bf16.h>

typedef __hip_bfloat16 bf16;
typedef __attribute__((ext_vector_type(8))) short short8;
typedef __attribute__((ext_vector_type(4))) float floatx4;
typedef __bf16 bf16x8 __attribute__((ext_vector_type(8)));

// ---------------- workspace layout ----------------
// float offsets
#define OFF_A1 0
#define OFF_C1 64
#define OFF_A2 128
#define OFF_C2 160
#define OFF_A3 192
#define OFF_C3 224
#define OFF_LP 256
#define OFF_P1S 512
#define OFF_P1Q 66048            // P1S + 1024*64
#define OFF_P2S 131584           // P1Q + 1024*64
#define OFF_P2Q 205312           // P2S + 2304*32
#define OFF_P3S 279040           // P2Q + 2304*32
#define OFF_P3Q 426496           // P3S + 4608*32
#define FLT_END 573952           // P3Q + 4608*32

// byte offsets
#define FW2_BYTE 2295808u        // FLT_END*4
#define FW3_BYTE 2332672u
#define X2_BYTE  33546240u       // x2 (36,27,1024,32) bf16
#define X3_BYTE  97247232u       // x3 (36,55,1024,32) bf16
#define O4_BYTE  227008512u      // o4 (1024,36,105) f32

// ---------------- d_out layout (float offsets) ----------------
#define OUT0 0
#define OUT1 153600
#define OUT2 155340
#define OUT3 2827980
#define OUT4 2858700
#define OUT5 3749580
#define OUT6 3780300
#define OUT7 3933900
#define OUT8 6606540
#define OUT9 6637260
#define OUT10 7528140

__device__ __forceinline__ bf16 f2b(float v){ return __float2bfloat16(v); }
__device__ __forceinline__ unsigned short f2bu(float v){ bf16 h = __float2bfloat16(v); return *(unsigned short*)&h; }

__device__ __forceinline__ floatx4 mfma16(short8 a, short8 b, floatx4 c){
  return __builtin_amdgcn_mfma_f32_16x16x32_bf16(__builtin_bit_cast(bf16x8, a),
                                                 __builtin_bit_cast(bf16x8, b), c, 0, 0, 0);
}

__device__ __forceinline__ unsigned int nrm2(unsigned int u, float a0, float c0, float a1, float c1){
  float x0 = __uint_as_float(u << 16);
  float x1 = __uint_as_float(u & 0xffff0000u);
  float y0 = fmaxf(fmaf(a0, x0, c0), 0.f);
  float y1 = fmaxf(fmaf(a1, x1, c1), 0.f);
  return (unsigned int)f2bu(y0) | ((unsigned int)f2bu(y1) << 16);
}

// ============ weight fragment prep ============
__global__ __launch_bounds__(256) void k_prep(const float* __restrict__ W2, const float* __restrict__ W3,
                                              unsigned short* __restrict__ fw2, unsigned short* __restrict__ fw3){
  const int t = blockIdx.x*256 + threadIdx.x;
  if (t < 2304){   // fw2: [tap9][mt2][kc2][L64][8]
    const int L = t & 63, kc = (t>>6)&1, mt = (t>>7)&1, tap = t>>8;
    const int co = mt*16 + (L&15), ci0 = kc*32 + ((L>>4)&3)*8;
    #pragma unroll
    for (int j = 0; j < 8; ++j)
      fw2[(size_t)t*8 + j] = f2bu(W2[((size_t)tap*64 + ci0 + j)*32 + co]);
  }
  if (t < 1152){   // fw3: [tap9][mt2][L64][8]
    const int L = t & 63, mt = (t>>6)&1, tap = t>>7;
    const int co = mt*16 + (L&15), ci0 = ((L>>4)&3)*8;
    #pragma unroll
    for (int j = 0; j < 8; ++j)
      fw3[(size_t)t*8 + j] = f2bu(W3[((size_t)tap*32 + ci0 + j)*32 + co]);
  }
}

// ============ layer-1 stats only (x1 never materialized; k2 recomputes it) ============
__global__ __launch_bounds__(256) void k_dc1(const float* __restrict__ Z, const float* __restrict__ W1,
                                             float* __restrict__ ws){
  const int b = blockIdx.x, t = threadIdx.x;
  __shared__ float zs[32];
  __shared__ float w1s[3*7*64];
  __shared__ float red[256];
  if (t < 32) zs[t] = Z[b*32 + t];
  for (int i = t; i < 1344; i += 256) w1s[i] = W1[i];
  __syncthreads();
  float lsum = 0.f, lsq = 0.f;
  for (int idx = t; idx < 15232; idx += 256){
    int co = idx & 63;
    int wo = (idx >> 6) % 7;
    int ho = idx / 448;
    int kw = 6 - wo;
    float y = 0.f;
    #pragma unroll
    for (int kh = 0; kh < 3; ++kh){
      int hi = ho + kh - 2;
      if (hi >= 0 && hi < 32) y += zs[hi] * w1s[(kh*7 + kw)*64 + co];
    }
    lsum += y; lsq += y*y;
  }
  red[t] = lsum; __syncthreads();
  if (t < 64) ws[OFF_P1S + b*64 + t] = red[t] + red[t+64] + red[t+128] + red[t+192];
  __syncthreads();
  red[t] = lsq; __syncthreads();
  if (t < 64) ws[OFF_P1Q + b*64 + t] = red[t] + red[t+64] + red[t+128] + red[t+192];
}

// ============ BN finalize: partials laid out [part][nch] ============
__global__ __launch_bounds__(256) void k_fin(float* __restrict__ ws, const float* __restrict__ g,
                                             const float* __restrict__ bb, int ps, int pq, int npart,
                                             int nch, float inv_n, int ao, int co, int zlp){
  const int c = blockIdx.x, t = threadIdx.x;
  __shared__ float r1[256], r2[256];
  float s = 0.f, q = 0.f;
  for (int i = t; i < npart; i += 256){ s += ws[ps + i*nch + c]; q += ws[pq + i*nch + c]; }
  r1[t] = s; r2[t] = q; __syncthreads();
  for (int off = 128; off > 0; off >>= 1){
    if (t < off){ r1[t] += r1[t+off]; r2[t] += r2[t+off]; }
    __syncthreads();
  }
  if (t == 0){
    float m  = r1[0] * inv_n;
    float v  = r2[0] * inv_n - m*m;
    float is = rsqrtf(v + 1e-5f);
    float a  = g[c] * is;
    ws[ao + c] = a;
    ws[co + c] = bb[c] - a*m;
  }
  if (zlp && c == 0 && t == 0) ws[OFF_LP] = 0.f;
}

// ============ deconv2 (MFMA): Z -> (recompute act1) -> x2 (36,27,1024,32) ============
// wo = 4*wi + 2 - kw; per idx (wo=8w+idx): kw=(2-idx)&3 static, wi=2w+(idx>>2) static
__global__ __launch_bounds__(256) void k2(const float* __restrict__ Z, const float* __restrict__ W1,
                                          const unsigned short* __restrict__ fw2,
                                          unsigned short* __restrict__ x2, float* __restrict__ ws){
  const int t = threadIdx.x;
  const int b0 = blockIdx.x*16, ho = blockIdx.y;
  __shared__ unsigned short sa[21*1024];     // act1 frags, later reused as store buffer
  __shared__ float zs[16][32];
  __shared__ float w1s[1344];
  __shared__ float sa1[64], sc1[64];
  __shared__ float sred[2][4][32];
  if (t < 64){ sa1[t] = ws[OFF_A1+t]; sc1[t] = ws[OFF_C1+t]; }
  for (int i = t; i < 512; i += 256) zs[i>>5][i&31] = Z[(b0 + (i>>5))*32 + (i&31)];
  for (int i = t; i < 1344; i += 256) w1s[i] = W1[i];
  __syncthreads();
  // recompute act1 for rows ho-2..ho, all 7 wi, 16 batches; store bf16 frags
  for (int c = t; c < 21*128; c += 256){
    const int p = c >> 7, g = c & 127;
    const int r = p/7, wi = p - r*7;
    const int hi = ho - 2 + r;
    const int b = g >> 3, kc = (g >> 2) & 1, j = g & 3;
    const int ci0 = kc*32 + j*8;
    unsigned int pk[4] = {0,0,0,0};
    if (hi >= 0 && hi < 34){
      const float* wp = &w1s[(6 - wi)*64 + ci0];
      #pragma unroll
      for (int e = 0; e < 8; e += 2){
        float y0 = 0.f, y1 = 0.f;
        #pragma unroll
        for (int kh = 0; kh < 3; ++kh){
          const int q = hi + kh - 2;
          if (q >= 0 && q < 32){
            float zv = zs[b][q];
            y0 += zv * wp[kh*448 + e];
            y1 += zv * wp[kh*448 + e + 1];
          }
        }
        float u0 = fmaxf(fmaf(sa1[ci0+e],   y0, sc1[ci0+e]),   0.f);
        float u1 = fmaxf(fmaf(sa1[ci0+e+1], y1, sc1[ci0+e+1]), 0.f);
        pk[e>>1] = (unsigned int)f2bu(u0) | ((unsigned int)f2bu(u1) << 16);
      }
    }
    *(uint4*)(sa + (size_t)p*1024 + kc*512 + (j*16 + b)*8) = *(uint4*)pk;
  }
  __syncthreads();
  const int w = t>>6, L = t&63;
  floatx4 acc[8][2];
  #pragma unroll
  for (int i = 0; i < 8; ++i){ acc[i][0] = (floatx4)0.f; acc[i][1] = (floatx4)0.f; }
  const int wiA = 2*w, wiB = (w < 3) ? 2*w + 1 : 2*w;
  for (int r = 0; r < 3; ++r){
    short8 af[3][2][2];
    #pragma unroll
    for (int kw = 0; kw < 3; ++kw)
      #pragma unroll
      for (int mt = 0; mt < 2; ++mt)
        #pragma unroll
        for (int kc = 0; kc < 2; ++kc)
          af[kw][mt][kc] = *(const short8*)(fw2 + ((((size_t)(r*3+kw)*2 + mt)*2 + kc)*64 + L)*8);
    const short8* pA = (const short8*)(sa + (size_t)(r*7 + wiA)*1024);
    const short8* pB = (const short8*)(sa + (size_t)(r*7 + wiB)*1024);
    short8 fa0 = pA[L], fa1 = pA[64+L];
    short8 fb0 = pB[L], fb1 = pB[64+L];
    #pragma unroll
    for (int idx = 0; idx < 8; ++idx){
      if (idx == 3 || idx == 7) continue;          // wo%4==3 cols are structurally zero
      const int kw = (2 - idx) & 3;                // compile-time
      const int half = idx >> 2;                   // compile-time: 0 -> wi=2w, 1 -> wi=2w+1
      if (half && w == 3) continue;                // uniform runtime guard
      short8 f0 = half ? fb0 : fa0;
      short8 f1 = half ? fb1 : fa1;
      #pragma unroll
      for (int mt = 0; mt < 2; ++mt){
        acc[idx][mt] = mfma16(af[kw][mt][0], f0, acc[idx][mt]);
        acc[idx][mt] = mfma16(af[kw][mt][1], f1, acc[idx][mt]);
      }
    }
  }
  // stats
  const int bL = L & 15, jj = (L>>4)&3;
  float ss[2][4] = {{0,0,0,0},{0,0,0,0}}, sq[2][4] = {{0,0,0,0},{0,0,0,0}};
  #pragma unroll
  for (int idx = 0; idx < 8; ++idx){
    if (8*w + idx >= 27) continue;
    #pragma unroll
    for (int mt = 0; mt < 2; ++mt){
      floatx4 a = acc[idx][mt];
      ss[mt][0] += a.x; ss[mt][1] += a.y; ss[mt][2] += a.z; ss[mt][3] += a.w;
      sq[mt][0] += a.x*a.x; sq[mt][1] += a.y*a.y; sq[mt][2] += a.z*a.z; sq[mt][3] += a.w*a.w;
    }
  }
  #pragma unroll
  for (int mt = 0; mt < 2; ++mt)
    #pragma unroll
    for (int r2 = 0; r2 < 4; ++r2){
      float v1 = ss[mt][r2], v2 = sq[mt][r2];
      for (int d = 1; d < 16; d <<= 1){ v1 += __shfl_xor(v1, d, 64); v2 += __shfl_xor(v2, d, 64); }
      if (bL == 0){
        int cch = mt*16 + jj*4 + r2;
        sred[0][w][cch] = v1;
        sred[1][w][cch] = v2;
      }
    }
  __syncthreads();            // all MFMA reads of sa done
  if (t < 64){
    const int cch = t & 31, j2 = t >> 5;
    float tot = sred[j2][0][cch] + sred[j2][1][cch] + sred[j2][2][cch] + sred[j2][3][cch];
    const int bid = blockIdx.y*64 + blockIdx.x;
    ws[(j2 ? OFF_P2Q : OFF_P2S) + bid*32 + cch] = tot;
  }
  // pack accumulators into LDS (wave-local, stride 36 shorts/batch)
  unsigned short* st = sa + w*4608;
  #pragma unroll
  for (int idx = 0; idx < 8; ++idx){
    if (8*w + idx >= 27) continue;
    #pragma unroll
    for (int mt = 0; mt < 2; ++mt){
      floatx4 a = acc[idx][mt];
      uint2 pk;
      pk.x = (unsigned int)f2bu(a.x) | ((unsigned int)f2bu(a.y) << 16);
      pk.y = (unsigned int)f2bu(a.z) | ((unsigned int)f2bu(a.w) << 16);
      *(uint2*)(st + idx*576 + bL*36 + mt*16 + jj*4) = pk;
    }
  }
  const int sb = L >> 2, q2 = L & 3;
  #pragma unroll
  for (int idx = 0; idx < 8; ++idx){
    const int wo = 8*w + idx;
    if (wo >= 27) continue;
    uint4 v = *(const uint4*)(st + idx*576 + sb*36 + q2*8);
    *(uint4*)(x2 + ((size_t)(ho*27+wo)*1024 + b0 + sb)*32 + q2*8) = v;
  }
}

// ============ deconv3 (MFMA): x2 -> x3 (36,55,1024,32) ============
// wo = 2*wi + 2 - kw; even s0 per wave => static tap pattern per idx
__global__ __launch_bounds__(256) void k3(const unsigned short* __restrict__ x2, const unsigned short* __restrict__ fw3,
                                          unsigned short* __restrict__ x3, float* __restrict__ ws){
  const int t = threadIdx.x;
  const int b0 = blockIdx.x*16, ho = blockIdx.y, z = blockIdx.z;
  const int wib = z*15;
  __shared__ unsigned short sa[48*512];      // 3 rows x 16 wi staged acts; reused as store buffer
  __shared__ float sa2[32], sc2[32];
  __shared__ float sred[2][4][32];
  if (t < 32){ sa2[t] = ws[OFF_A2+t]; sc2[t] = ws[OFF_C2+t]; }
  __syncthreads();
  for (int c = t; c < 48*64; c += 256){
    const int p = c >> 6, g = c & 63;
    const int r = p >> 4, wl = p & 15;
    const int wi = wib + wl;
    const int hi = ho - 1 + r;
    const int b = g >> 2, j = g & 3;
    const int ci0 = j*8;
    uint4 v = make_uint4(0,0,0,0);
    if (hi >= 0 && hi < 36 && wi < 27){
      v = *(const uint4*)(x2 + ((size_t)(hi*27+wi)*1024 + b0 + b)*32 + ci0);
      v.x = nrm2(v.x, sa2[ci0],   sc2[ci0],   sa2[ci0+1], sc2[ci0+1]);
      v.y = nrm2(v.y, sa2[ci0+2], sc2[ci0+2], sa2[ci0+3], sc2[ci0+3]);
      v.z = nrm2(v.z, sa2[ci0+4], sc2[ci0+4], sa2[ci0+5], sc2[ci0+5]);
      v.w = nrm2(v.w, sa2[ci0+6], sc2[ci0+6], sa2[ci0+7], sc2[ci0+7]);
    }
    *(uint4*)(sa + (size_t)p*512 + (j*16 + b)*8) = v;
  }
  __syncthreads();
  const int w = t>>6, L = t&63;
  const int s0 = z ? (32 + 6*w) : (8*w);     // always even
  const int h2 = s0 >> 1;
  const int nvalid = z ? ((w == 3) ? 5 : 6) : 8;
  floatx4 acc[8][2];
  #pragma unroll
  for (int i = 0; i < 8; ++i){ acc[i][0] = (floatx4)0.f; acc[i][1] = (floatx4)0.f; }
  for (int r = 0; r < 3; ++r){
    short8 af[3][2];
    #pragma unroll
    for (int kw = 0; kw < 3; ++kw)
      #pragma unroll
      for (int mt = 0; mt < 2; ++mt)
        af[kw][mt] = *(const short8*)(fw3 + (((size_t)(r*3+kw)*2 + mt)*64 + L)*8);
    short8 bb[5];
    #pragma unroll
    for (int d = 0; d < 5; ++d){
      const int wi = h2 - 1 + d;
      short8 v = (short8)0;
      if (wi >= 0 && wi < 27)
        v = *(const short8*)(sa + (size_t)(r*16 + wi - wib)*512 + L*8);
      bb[d] = v;
    }
    #pragma unroll
    for (int idx = 0; idx < 8; ++idx){
      if (idx >= nvalid) continue;           // uniform runtime guard
      if ((idx & 1) == 0){
        const int d = idx >> 1;              // kw=0: wi=h2+idx/2-1 ; kw=2: wi=h2+idx/2
        #pragma unroll
        for (int mt = 0; mt < 2; ++mt){
          acc[idx][mt] = mfma16(af[0][mt], bb[d],   acc[idx][mt]);
          acc[idx][mt] = mfma16(af[2][mt], bb[d+1], acc[idx][mt]);
        }
      } else {
        const int d = ((idx - 1) >> 1) + 1;  // kw=1: wi=h2+(idx-1)/2
        #pragma unroll
        for (int mt = 0; mt < 2; ++mt)
          acc[idx][mt] = mfma16(af[1][mt], bb[d], acc[idx][mt]);
      }
    }
  }
  const int bL = L & 15, jj = (L>>4)&3;
  float ss[2][4] = {{0,0,0,0},{0,0,0,0}}, sq[2][4] = {{0,0,0,0},{0,0,0,0}};
  #pragma unroll
  for (int idx = 0; idx < 8; ++idx){
    if (idx >= nvalid) continue;
    #pragma unroll
    for (int mt = 0; mt < 2; ++mt){
      floatx4 a = acc[idx][mt];
      ss[mt][0] += a.x; ss[mt][1] += a.y; ss[mt][2] += a.z; ss[mt][3] += a.w;
      sq[mt][0] += a.x*a.x; sq[mt][1] += a.y*a.y; sq[mt][2] += a.z*a.z; sq[mt][3] += a.w*a.w;
    }
  }
  #pragma unroll
  for (int mt = 0; mt < 2; ++mt)
    #pragma unroll
    for (int r2 = 0; r2 < 4; ++r2){
      float v1 = ss[mt][r2], v2 = sq[mt][r2];
      for (int d = 1; d < 16; d <<= 1){ v1 += __shfl_xor(v1, d, 64); v2 += __shfl_xor(v2, d, 64); }
      if (bL == 0){
        int cch = mt*16 + jj*4 + r2;
        sred[0][w][cch] = v1;
        sred[1][w][cch] = v2;
      }
    }
  __syncthreads();
  if (t < 64){
    const int cch = t & 31, j2 = t >> 5;
    float tot = sred[j2][0][cch] + sred[j2][1][cch] + sred[j2][2][cch] + sred[j2][3][cch];
    const int bid = (z*36 + blockIdx.y)*64 + blockIdx.x;
    ws[(j2 ? OFF_P3Q : OFF_P3S) + bid*32 + cch] = tot;
  }
  unsigned short* st = sa + w*4608;
  #pragma unroll
  for (int idx = 0; idx < 8; ++idx){
    if (idx >= nvalid) continue;
    #pragma unroll
    for (int mt = 0; mt < 2; ++mt){
      floatx4 a = acc[idx][mt];
      uint2 pk;
      pk.x = (unsigned int)f2bu(a.x) | ((unsigned int)f2bu(a.y) << 16);
      pk.y = (unsigned int)f2bu(a.z) | ((unsigned int)f2bu(a.w) << 16);
      *(uint2*)(st + idx*576 + bL*36 + mt*16 + jj*4) = pk;
    }
  }
  const int sb = L >> 2, q2 = L & 3;
  #pragma unroll
  for (int idx = 0; idx < 8; ++idx){
    if (idx >= nvalid) continue;
    const int wo = s0 + idx;
    uint4 v = *(const uint4*)(st + idx*576 + sb*36 + q2*8);
    *(uint4*)(x3 + ((size_t)(ho*55+wo)*1024 + b0 + sb)*32 + q2*8) = v;
  }
}

// ============ deconv4 (VALU): x3 -> o4 (B,36,105) via LDS row transpose ============
__global__ __launch_bounds__(256) void k_dc4(const unsigned short* __restrict__ x3, const float* __restrict__ W4,
                                             float* __restrict__ o4, const float* __restrict__ ws){
  const int t = threadIdx.x;
  const int lb = t & 63, qg = t >> 6;
  const int b = blockIdx.x*64 + lb;
  const int h3 = blockIdx.y*3;
  __shared__ float w4s[480];
  __shared__ float a3s[32], c3s[32];
  __shared__ float rowbuf[64*109];
  if (t < 32){ a3s[t] = ws[OFF_A3+t]; c3s[t] = ws[OFF_C3+t]; }
  for (int i = t; i < 480; i += 256) w4s[i] = W4[i];
  __syncthreads();
  for (int hl = 0; hl < 3; ++hl){
    const int ho = h3 + hl;
    for (int g = qg; g < 27; g += 4){
      float out[4] = {0.f, 0.f, 0.f, 0.f};
      for (int r = 0; r < 3; ++r){
        const int hi = ho - 1 + r;
        if (hi < 0 || hi >= 36) continue;
        #pragma unroll
        for (int dwi = 0; dwi < 4; ++dwi){
          const int wi = 2*g + dwi;
          if (wi >= 55) continue;
          float fa[32];
          const unsigned short* px = x3 + ((size_t)(hi*55+wi)*1024 + b)*32;
          #pragma unroll
          for (int q = 0; q < 4; ++q){
            uint4 v = *(const uint4*)(px + q*8);
            unsigned int uu[4] = {v.x, v.y, v.z, v.w};
            #pragma unroll
            for (int k2i = 0; k2i < 4; ++k2i){
              int ci = q*8 + k2i*2;
              float x0 = __uint_as_float(uu[k2i] << 16);
              float x1f = __uint_as_float(uu[k2i] & 0xffff0000u);
              fa[ci]   = fmaxf(fmaf(a3s[ci],   x0,  c3s[ci]),   0.f);
              fa[ci+1] = fmaxf(fmaf(a3s[ci+1], x1f, c3s[ci+1]), 0.f);
            }
          }
          #pragma unroll
          for (int s = 0; s < 4; ++s){
            const int kw = 2*dwi - s;
            if (kw < 0 || kw >= 5) continue;
            const float* wr = &w4s[(r*5 + kw)*32];
            float a = 0.f;
            #pragma unroll
            for (int ci = 0; ci < 32; ++ci) a += fa[ci]*wr[ci];
            out[s] += a;
          }
        }
      }
      #pragma unroll
      for (int s = 0; s < 4; ++s){
        const int wo = 4*g + s;
        if (wo < 105) rowbuf[lb*109 + wo] = out[s];
      }
    }
    __syncthreads();
    for (int i = t; i < 6720; i += 256){
      const int bb = i / 105, wo = i - bb*105;
      o4[(size_t)(blockIdx.x*64 + bb)*3780 + ho*105 + wo] = rowbuf[bb*109 + wo];
    }
    __syncthreads();
  }
}

// ============ node softmax / outputs ============
__global__ __launch_bounds__(256) void k_node(const float* __restrict__ o4, float* __restrict__ dout,
                                              float* __restrict__ ws){
  const int t = threadIdx.x;
  const int tg = blockIdx.x*256 + t;
  __shared__ float red[256];
  float lp = 0.f;
  {
    int b = tg / 30, n = tg - b*30;
    const float* p = o4 + (size_t)b*3780 + n*126;
    float l[6]; float mx = -1e30f;
    #pragma unroll
    for (int j = 0; j < 6; ++j){ l[j] = p[j]; mx = fmaxf(mx, l[j]); }
    float e[6]; float s = 0.f;
    #pragma unroll
    for (int j = 0; j < 6; ++j){ e[j] = expf(l[j] - mx); s += e[j]; }
    float inv = 1.f / s;
    int am = 0; float best = e[0];
    #pragma unroll
    for (int j = 1; j < 6; ++j){ if (e[j] > best){ best = e[j]; am = j; } }
    #pragma unroll
    for (int j = 0; j < 5; ++j) dout[OUT0 + (size_t)tg*5 + j] = e[j+1]*inv;
    dout[OUT3 + tg] = 1.f - e[0]*inv;
    #pragma unroll
    for (int j = 0; j < 5; ++j) dout[OUT6 + (size_t)tg*5 + j] = (am == j+1) ? 1.f : 0.f;
    dout[OUT8 + tg] = (am != 0) ? 1.f : 0.f;
    dout[OUT5 + tg] = (float)b;
    lp = logf(best*inv + 1e-7f);
  }
  red[t] = lp; __syncthreads();
  for (int off = 128; off > 0; off >>= 1){ if (t < off) red[t] += red[t+off]; __syncthreads(); }
  if (t == 0) atomicAdd(&ws[OFF_LP], red[0]);
}

// ============ edge softmax / outputs ============
__global__ __launch_bounds__(256) void k_edge(const float* __restrict__ o4, float* __restrict__ dout,
                                              float* __restrict__ ws){
  const int t = threadIdx.x;
  const int tg = blockIdx.x*256 + t;
  __shared__ float red[256];
  float lp = 0.f;
  {
    int b = tg / 435, k = tg - b*435;
    int i = 0, rem = k;
    while (rem >= 29 - i){ rem -= 29 - i; ++i; }
    int j = i + 1 + rem;
    const float* p = o4 + (size_t)b*3780 + i*126 + 6 + j*4;
    float l0 = p[0], l1 = p[1], l2 = p[2], l3 = p[3];
    float mx = fmaxf(fmaxf(l0, l1), fmaxf(l2, l3));
    float e0 = expf(l0-mx), e1 = expf(l1-mx), e2 = expf(l2-mx), e3 = expf(l3-mx);
    float inv = 1.f / (e0 + e1 + e2 + e3);
    float pr0 = e0*inv, pr1 = e1*inv, pr2 = e2*inv, pr3 = e3*inv;
    int am = 0; float best = pr0;
    if (pr1 > best){ best = pr1; am = 1; }
    if (pr2 > best){ best = pr2; am = 2; }
    if (pr3 > best){ best = pr3; am = 3; }
    size_t e1i = (size_t)b*870 + k, e2i = e1i + 435;
    dout[OUT2 + e1i*3 + 0] = pr1; dout[OUT2 + e1i*3 + 1] = pr2; dout[OUT2 + e1i*3 + 2] = pr3;
    dout[OUT2 + e2i*3 + 0] = pr1; dout[OUT2 + e2i*3 + 1] = pr2; dout[OUT2 + e2i*3 + 2] = pr3;
    dout[OUT4 + e1i] = 1.f - pr0;  dout[OUT4 + e2i] = 1.f - pr0;
    float h1 = (am == 1) ? 1.f : 0.f, h2 = (am == 2) ? 1.f : 0.f, h3 = (am == 3) ? 1.f : 0.f;
    dout[OUT7 + e1i*3 + 0] = h1; dout[OUT7 + e1i*3 + 1] = h2; dout[OUT7 + e1i*3 + 2] = h3;
    dout[OUT7 + e2i*3 + 0] = h1; dout[OUT7 + e2i*3 + 1] = h2; dout[OUT7 + e2i*3 + 2] = h3;
    dout[OUT9 + e1i] = (am != 0) ? 1.f : 0.f;  dout[OUT9 + e2i] = (am != 0) ? 1.f : 0.f;
    if (b == 0){
      dout[OUT1 + k]        = (float)i;
      dout[OUT1 + 435 + k]  = (float)j;
      dout[OUT1 + 870 + k]  = (float)j;
      dout[OUT1 + 1305 + k] = (float)i;
    }
    lp = logf(best + 1e-7f);
  }
  red[t] = lp; __syncthreads();
  for (int off = 128; off > 0; off >>= 1){ if (t < off) red[t] += red[t+off]; __syncthreads(); }
  if (t == 0) atomicAdd(&ws[OFF_LP], red[0]);
}

__global__ void k_lp_copy(float* __restrict__ dout, const float* __restrict__ ws){
  if (threadIdx.x == 0 && blockIdx.x == 0) dout[OUT10] = ws[OFF_LP];
}

extern "C" void kernel_launch(void* const* d_in, const int* in_sizes, int n_in,
                              void* d_out, int out_size, void* d_ws, size_t ws_size,
                              hipStream_t stream) {
  const float* Z  = (const float*)d_in[0];
  const float* W1 = (const float*)d_in[1];
  const float* W2 = (const float*)d_in[2];
  const float* W3 = (const float*)d_in[3];
  const float* W4 = (const float*)d_in[4];
  const float* g1 = (const float*)d_in[5];
  const float* b1 = (const float*)d_in[6];
  const float* g2 = (const float*)d_in[7];
  const float* b2 = (const float*)d_in[8];
  const float* g3 = (const float*)d_in[9];
  const float* b3 = (const float*)d_in[10];

  float* ws  = (float*)d_ws;
  char*  wsb = (char*)d_ws;
  unsigned short* fw2 = (unsigned short*)(wsb + FW2_BYTE);
  unsigned short* fw3 = (unsigned short*)(wsb + FW3_BYTE);
  unsigned short* x2u = (unsigned short*)(wsb + X2_BYTE);
  unsigned short* x3u = (unsigned short*)(wsb + X3_BYTE);
  float*          o4  = (float*)(wsb + O4_BYTE);
  float* dout = (float*)d_out;
  (void)in_sizes; (void)n_in; (void)out_size; (void)ws_size;

  k_prep<<<dim3(9), dim3(256), 0, stream>>>(W2, W3, fw2, fw3);
  k_dc1<<<dim3(1024), dim3(256), 0, stream>>>(Z, W1, ws);
  k_fin<<<dim3(64), dim3(256), 0, stream>>>(ws, g1, b1, OFF_P1S, OFF_P1Q, 1024, 64,
                                            1.f/243712.f, OFF_A1, OFF_C1, 0);
  k2<<<dim3(64, 36), dim3(256), 0, stream>>>(Z, W1, fw2, x2u, ws);
  k_fin<<<dim3(32), dim3(256), 0, stream>>>(ws, g2, b2, OFF_P2S, OFF_P2Q, 2304, 32,
                                            1.f/995328.f, OFF_A2, OFF_C2, 0);
  k3<<<dim3(64, 36, 2), dim3(256), 0, stream>>>(x2u, fw3, x3u, ws);
  k_fin<<<dim3(32), dim3(256), 0, stream>>>(ws, g3, b3, OFF_P3S, OFF_P3Q, 4608, 32,
                                            1.f/2027520.f, OFF_A3, OFF_C3, 1);
  k_dc4<<<dim3(16, 12), dim3(256), 0, stream>>>(x3u, W4, o4, ws);
  k_node<<<dim3(120), dim3(256), 0, stream>>>(o4, dout, ws);
  k_edge<<<dim3(1740), dim3(256), 0, stream>>>(o4, dout, ws);
  k_lp_copy<<<dim3(1), dim3(64), 0, stream>>>(dout, ws);
}

// Round 6
// 339.850 us; speedup vs baseline: 2.6521x; 1.4946x over previous
//
#include <hip/hip_runtime.h>
#include <hip/hip_bf16.h>

typedef __hip_bfloat16 bf16;
typedef __attribute__((ext_vector_type(8))) short short8;
typedef __attribute__((ext_vector_type(4))) float floatx4;
typedef __bf16 bf16x8 __attribute__((ext_vector_type(8)));

// ---------------- workspace layout ----------------
// float offsets
#define OFF_A1 0
#define OFF_C1 64
#define OFF_A2 128
#define OFF_C2 160
#define OFF_A3 192
#define OFF_C3 224
#define OFF_LP 256
#define OFF_P1S 512
#define OFF_P1Q 66048            // P1S + 1024*64
#define OFF_P2S 131584           // P1Q + 1024*64
#define OFF_P2Q 205312           // P2S + 2304*32
#define OFF_P3S 279040           // P2Q + 2304*32
#define OFF_P3Q 426496           // P3S + 4608*32
#define FLT_END 573952           // P3Q + 4608*32

// byte offsets
#define FW2_BYTE 2295808u        // FLT_END*4
#define FW3_BYTE 2332672u        // + 2304*8*2
#define FW4_BYTE 2351104u        // + 1152*8*2 ; fw4: [r3][d10][L64][8] = 30720 B
#define X2_BYTE  33546240u       // x2 (36,27,1024,32) bf16
#define X3_BYTE  97247232u       // x3 (36,55,1024,32) bf16
#define O4_BYTE  227008512u      // o4 (1024,36,105) f32

// ---------------- d_out layout (float offsets) ----------------
#define OUT0 0
#define OUT1 153600
#define OUT2 155340
#define OUT3 2827980
#define OUT4 2858700
#define OUT5 3749580
#define OUT6 3780300
#define OUT7 3933900
#define OUT8 6606540
#define OUT9 6637260
#define OUT10 7528140

__device__ __forceinline__ bf16 f2b(float v){ return __float2bfloat16(v); }
__device__ __forceinline__ unsigned short f2bu(float v){ bf16 h = __float2bfloat16(v); return *(unsigned short*)&h; }

__device__ __forceinline__ floatx4 mfma16(short8 a, short8 b, floatx4 c){
  return __builtin_amdgcn_mfma_f32_16x16x32_bf16(__builtin_bit_cast(bf16x8, a),
                                                 __builtin_bit_cast(bf16x8, b), c, 0, 0, 0);
}

__device__ __forceinline__ unsigned int nrm2(unsigned int u, float a0, float c0, float a1, float c1){
  float x0 = __uint_as_float(u << 16);
  float x1 = __uint_as_float(u & 0xffff0000u);
  float y0 = fmaxf(fmaf(a0, x0, c0), 0.f);
  float y1 = fmaxf(fmaf(a1, x1, c1), 0.f);
  return (unsigned int)f2bu(y0) | ((unsigned int)f2bu(y1) << 16);
}

// ============ weight fragment prep ============
__global__ __launch_bounds__(256) void k_prep(const float* __restrict__ W2, const float* __restrict__ W3,
                                              const float* __restrict__ W4,
                                              unsigned short* __restrict__ fw2, unsigned short* __restrict__ fw3,
                                              unsigned short* __restrict__ fw4){
  const int t = blockIdx.x*256 + threadIdx.x;
  if (t < 2304){   // fw2: [tap9][mt2][kc2][L64][8]
    const int L = t & 63, kc = (t>>6)&1, mt = (t>>7)&1, tap = t>>8;
    const int co = mt*16 + (L&15), ci0 = kc*32 + ((L>>4)&3)*8;
    #pragma unroll
    for (int j = 0; j < 8; ++j)
      fw2[(size_t)t*8 + j] = f2bu(W2[((size_t)tap*64 + ci0 + j)*32 + co]);
  }
  if (t < 1152){   // fw3: [tap9][mt2][L64][8]
    const int L = t & 63, mt = (t>>6)&1, tap = t>>7;
    const int co = mt*16 + (L&15), ci0 = ((L>>4)&3)*8;
    #pragma unroll
    for (int j = 0; j < 8; ++j)
      fw3[(size_t)t*8 + j] = f2bu(W3[((size_t)tap*32 + ci0 + j)*32 + co]);
  }
  if (t < 1920){   // fw4: banded layer-4 A-frags [r3][d10][L64][8]; A[m][ci] = W4[r][kw=2d-m][ci]
    const int L = t & 63, d = (t>>6) % 10, r = t / 640;
    const int m = L & 15, ci0 = ((L>>4)&3)*8;
    const int kw = 2*d - m;
    #pragma unroll
    for (int j = 0; j < 8; ++j)
      fw4[(size_t)t*8 + j] = (kw >= 0 && kw < 5) ? f2bu(W4[(r*5 + kw)*32 + ci0 + j])
                                                 : (unsigned short)0;
  }
}

// ============ layer-1 stats only (x1 never materialized; k2 recomputes it) ============
__global__ __launch_bounds__(256) void k_dc1(const float* __restrict__ Z, const float* __restrict__ W1,
                                             float* __restrict__ ws){
  const int b = blockIdx.x, t = threadIdx.x;
  __shared__ float zs[32];
  __shared__ float w1s[3*7*64];
  __shared__ float red[256];
  if (t < 32) zs[t] = Z[b*32 + t];
  for (int i = t; i < 1344; i += 256) w1s[i] = W1[i];
  __syncthreads();
  float lsum = 0.f, lsq = 0.f;
  for (int idx = t; idx < 15232; idx += 256){
    int co = idx & 63;
    int wo = (idx >> 6) % 7;
    int ho = idx / 448;
    int kw = 6 - wo;
    float y = 0.f;
    #pragma unroll
    for (int kh = 0; kh < 3; ++kh){
      int hi = ho + kh - 2;
      if (hi >= 0 && hi < 32) y += zs[hi] * w1s[(kh*7 + kw)*64 + co];
    }
    lsum += y; lsq += y*y;
  }
  red[t] = lsum; __syncthreads();
  if (t < 64) ws[OFF_P1S + b*64 + t] = red[t] + red[t+64] + red[t+128] + red[t+192];
  __syncthreads();
  red[t] = lsq; __syncthreads();
  if (t < 64) ws[OFF_P1Q + b*64 + t] = red[t] + red[t+64] + red[t+128] + red[t+192];
}

// ============ BN finalize: partials laid out [part][nch] ============
__global__ __launch_bounds__(256) void k_fin(float* __restrict__ ws, const float* __restrict__ g,
                                             const float* __restrict__ bb, int ps, int pq, int npart,
                                             int nch, float inv_n, int ao, int co, int zlp){
  const int c = blockIdx.x, t = threadIdx.x;
  __shared__ float r1[256], r2[256];
  float s = 0.f, q = 0.f;
  for (int i = t; i < npart; i += 256){ s += ws[ps + i*nch + c]; q += ws[pq + i*nch + c]; }
  r1[t] = s; r2[t] = q; __syncthreads();
  for (int off = 128; off > 0; off >>= 1){
    if (t < off){ r1[t] += r1[t+off]; r2[t] += r2[t+off]; }
    __syncthreads();
  }
  if (t == 0){
    float m  = r1[0] * inv_n;
    float v  = r2[0] * inv_n - m*m;
    float is = rsqrtf(v + 1e-5f);
    float a  = g[c] * is;
    ws[ao + c] = a;
    ws[co + c] = bb[c] - a*m;
  }
  if (zlp && c == 0 && t == 0) ws[OFF_LP] = 0.f;
}

// ============ deconv2 (MFMA): Z -> (recompute act1) -> x2 (36,27,1024,32) ============
// wo = 4*wi + 2 - kw; per idx (wo=8w+idx): kw=(2-idx)&3 static, wi=2w+(idx>>2) static
__global__ __launch_bounds__(256) void k2(const float* __restrict__ Z, const float* __restrict__ W1,
                                          const unsigned short* __restrict__ fw2,
                                          unsigned short* __restrict__ x2, float* __restrict__ ws){
  const int t = threadIdx.x;
  const int b0 = blockIdx.x*16, ho = blockIdx.y;
  __shared__ unsigned short sa[21*1024];     // act1 frags, later reused as store buffer
  __shared__ float zs[16][32];
  __shared__ float w1s[1344];
  __shared__ float sa1[64], sc1[64];
  __shared__ float sred[2][4][32];
  if (t < 64){ sa1[t] = ws[OFF_A1+t]; sc1[t] = ws[OFF_C1+t]; }
  for (int i = t; i < 512; i += 256) zs[i>>5][i&31] = Z[(b0 + (i>>5))*32 + (i&31)];
  for (int i = t; i < 1344; i += 256) w1s[i] = W1[i];
  __syncthreads();
  for (int c = t; c < 21*128; c += 256){
    const int p = c >> 7, g = c & 127;
    const int r = p/7, wi = p - r*7;
    const int hi = ho - 2 + r;
    const int b = g >> 3, kc = (g >> 2) & 1, j = g & 3;
    const int ci0 = kc*32 + j*8;
    unsigned int pk[4] = {0,0,0,0};
    if (hi >= 0 && hi < 34){
      const float* wp = &w1s[(6 - wi)*64 + ci0];
      #pragma unroll
      for (int e = 0; e < 8; e += 2){
        float y0 = 0.f, y1 = 0.f;
        #pragma unroll
        for (int kh = 0; kh < 3; ++kh){
          const int q = hi + kh - 2;
          if (q >= 0 && q < 32){
            float zv = zs[b][q];
            y0 += zv * wp[kh*448 + e];
            y1 += zv * wp[kh*448 + e + 1];
          }
        }
        float u0 = fmaxf(fmaf(sa1[ci0+e],   y0, sc1[ci0+e]),   0.f);
        float u1 = fmaxf(fmaf(sa1[ci0+e+1], y1, sc1[ci0+e+1]), 0.f);
        pk[e>>1] = (unsigned int)f2bu(u0) | ((unsigned int)f2bu(u1) << 16);
      }
    }
    *(uint4*)(sa + (size_t)p*1024 + kc*512 + (j*16 + b)*8) = *(uint4*)pk;
  }
  __syncthreads();
  const int w = t>>6, L = t&63;
  floatx4 acc[8][2];
  #pragma unroll
  for (int i = 0; i < 8; ++i){ acc[i][0] = (floatx4)0.f; acc[i][1] = (floatx4)0.f; }
  const int wiA = 2*w, wiB = (w < 3) ? 2*w + 1 : 2*w;
  for (int r = 0; r < 3; ++r){
    short8 af[3][2][2];
    #pragma unroll
    for (int kw = 0; kw < 3; ++kw)
      #pragma unroll
      for (int mt = 0; mt < 2; ++mt)
        #pragma unroll
        for (int kc = 0; kc < 2; ++kc)
          af[kw][mt][kc] = *(const short8*)(fw2 + ((((size_t)(r*3+kw)*2 + mt)*2 + kc)*64 + L)*8);
    const short8* pA = (const short8*)(sa + (size_t)(r*7 + wiA)*1024);
    const short8* pB = (const short8*)(sa + (size_t)(r*7 + wiB)*1024);
    short8 fa0 = pA[L], fa1 = pA[64+L];
    short8 fb0 = pB[L], fb1 = pB[64+L];
    #pragma unroll
    for (int idx = 0; idx < 8; ++idx){
      if (idx == 3 || idx == 7) continue;          // wo%4==3 cols are structurally zero
      const int kw = (2 - idx) & 3;                // compile-time
      const int half = idx >> 2;                   // compile-time
      if (half && w == 3) continue;                // uniform runtime guard
      short8 f0 = half ? fb0 : fa0;
      short8 f1 = half ? fb1 : fa1;
      #pragma unroll
      for (int mt = 0; mt < 2; ++mt){
        acc[idx][mt] = mfma16(af[kw][mt][0], f0, acc[idx][mt]);
        acc[idx][mt] = mfma16(af[kw][mt][1], f1, acc[idx][mt]);
      }
    }
  }
  const int bL = L & 15, jj = (L>>4)&3;
  float ss[2][4] = {{0,0,0,0},{0,0,0,0}}, sq[2][4] = {{0,0,0,0},{0,0,0,0}};
  #pragma unroll
  for (int idx = 0; idx < 8; ++idx){
    if (8*w + idx >= 27) continue;
    #pragma unroll
    for (int mt = 0; mt < 2; ++mt){
      floatx4 a = acc[idx][mt];
      ss[mt][0] += a.x; ss[mt][1] += a.y; ss[mt][2] += a.z; ss[mt][3] += a.w;
      sq[mt][0] += a.x*a.x; sq[mt][1] += a.y*a.y; sq[mt][2] += a.z*a.z; sq[mt][3] += a.w*a.w;
    }
  }
  #pragma unroll
  for (int mt = 0; mt < 2; ++mt)
    #pragma unroll
    for (int r2 = 0; r2 < 4; ++r2){
      float v1 = ss[mt][r2], v2 = sq[mt][r2];
      for (int d = 1; d < 16; d <<= 1){ v1 += __shfl_xor(v1, d, 64); v2 += __shfl_xor(v2, d, 64); }
      if (bL == 0){
        int cch = mt*16 + jj*4 + r2;
        sred[0][w][cch] = v1;
        sred[1][w][cch] = v2;
      }
    }
  __syncthreads();
  if (t < 64){
    const int cch = t & 31, j2 = t >> 5;
    float tot = sred[j2][0][cch] + sred[j2][1][cch] + sred[j2][2][cch] + sred[j2][3][cch];
    const int bid = blockIdx.y*64 + blockIdx.x;
    ws[(j2 ? OFF_P2Q : OFF_P2S) + bid*32 + cch] = tot;
  }
  unsigned short* st = sa + w*4608;
  #pragma unroll
  for (int idx = 0; idx < 8; ++idx){
    if (8*w + idx >= 27) continue;
    #pragma unroll
    for (int mt = 0; mt < 2; ++mt){
      floatx4 a = acc[idx][mt];
      uint2 pk;
      pk.x = (unsigned int)f2bu(a.x) | ((unsigned int)f2bu(a.y) << 16);
      pk.y = (unsigned int)f2bu(a.z) | ((unsigned int)f2bu(a.w) << 16);
      *(uint2*)(st + idx*576 + bL*36 + mt*16 + jj*4) = pk;
    }
  }
  const int sb = L >> 2, q2 = L & 3;
  #pragma unroll
  for (int idx = 0; idx < 8; ++idx){
    const int wo = 8*w + idx;
    if (wo >= 27) continue;
    uint4 v = *(const uint4*)(st + idx*576 + sb*36 + q2*8);
    *(uint4*)(x2 + ((size_t)(ho*27+wo)*1024 + b0 + sb)*32 + q2*8) = v;
  }
}

// ============ deconv3 (MFMA): x2 -> x3 (36,55,1024,32) ============
// wo = 2*wi + 2 - kw; even s0 per wave => static tap pattern per idx
__global__ __launch_bounds__(256) void k3(const unsigned short* __restrict__ x2, const unsigned short* __restrict__ fw3,
                                          unsigned short* __restrict__ x3, float* __restrict__ ws){
  const int t = threadIdx.x;
  const int b0 = blockIdx.x*16, ho = blockIdx.y, z = blockIdx.z;
  const int wib = z*15;
  __shared__ unsigned short sa[48*512];
  __shared__ float sa2[32], sc2[32];
  __shared__ float sred[2][4][32];
  if (t < 32){ sa2[t] = ws[OFF_A2+t]; sc2[t] = ws[OFF_C2+t]; }
  __syncthreads();
  for (int c = t; c < 48*64; c += 256){
    const int p = c >> 6, g = c & 63;
    const int r = p >> 4, wl = p & 15;
    const int wi = wib + wl;
    const int hi = ho - 1 + r;
    const int b = g >> 2, j = g & 3;
    const int ci0 = j*8;
    uint4 v = make_uint4(0,0,0,0);
    if (hi >= 0 && hi < 36 && wi < 27){
      v = *(const uint4*)(x2 + ((size_t)(hi*27+wi)*1024 + b0 + b)*32 + ci0);
      v.x = nrm2(v.x, sa2[ci0],   sc2[ci0],   sa2[ci0+1], sc2[ci0+1]);
      v.y = nrm2(v.y, sa2[ci0+2], sc2[ci0+2], sa2[ci0+3], sc2[ci0+3]);
      v.z = nrm2(v.z, sa2[ci0+4], sc2[ci0+4], sa2[ci0+5], sc2[ci0+5]);
      v.w = nrm2(v.w, sa2[ci0+6], sc2[ci0+6], sa2[ci0+7], sc2[ci0+7]);
    }
    *(uint4*)(sa + (size_t)p*512 + (j*16 + b)*8) = v;
  }
  __syncthreads();
  const int w = t>>6, L = t&63;
  const int s0 = z ? (32 + 6*w) : (8*w);     // always even
  const int h2 = s0 >> 1;
  const int nvalid = z ? ((w == 3) ? 5 : 6) : 8;
  floatx4 acc[8][2];
  #pragma unroll
  for (int i = 0; i < 8; ++i){ acc[i][0] = (floatx4)0.f; acc[i][1] = (floatx4)0.f; }
  for (int r = 0; r < 3; ++r){
    short8 af[3][2];
    #pragma unroll
    for (int kw = 0; kw < 3; ++kw)
      #pragma unroll
      for (int mt = 0; mt < 2; ++mt)
        af[kw][mt] = *(const short8*)(fw3 + (((size_t)(r*3+kw)*2 + mt)*64 + L)*8);
    short8 bb[5];
    #pragma unroll
    for (int d = 0; d < 5; ++d){
      const int wi = h2 - 1 + d;
      short8 v = (short8)0;
      if (wi >= 0 && wi < 27)
        v = *(const short8*)(sa + (size_t)(r*16 + wi - wib)*512 + L*8);
      bb[d] = v;
    }
    #pragma unroll
    for (int idx = 0; idx < 8; ++idx){
      if (idx >= nvalid) continue;
      if ((idx & 1) == 0){
        const int d = idx >> 1;
        #pragma unroll
        for (int mt = 0; mt < 2; ++mt){
          acc[idx][mt] = mfma16(af[0][mt], bb[d],   acc[idx][mt]);
          acc[idx][mt] = mfma16(af[2][mt], bb[d+1], acc[idx][mt]);
        }
      } else {
        const int d = ((idx - 1) >> 1) + 1;
        #pragma unroll
        for (int mt = 0; mt < 2; ++mt)
          acc[idx][mt] = mfma16(af[1][mt], bb[d], acc[idx][mt]);
      }
    }
  }
  const int bL = L & 15, jj = (L>>4)&3;
  float ss[2][4] = {{0,0,0,0},{0,0,0,0}}, sq[2][4] = {{0,0,0,0},{0,0,0,0}};
  #pragma unroll
  for (int idx = 0; idx < 8; ++idx){
    if (idx >= nvalid) continue;
    #pragma unroll
    for (int mt = 0; mt < 2; ++mt){
      floatx4 a = acc[idx][mt];
      ss[mt][0] += a.x; ss[mt][1] += a.y; ss[mt][2] += a.z; ss[mt][3] += a.w;
      sq[mt][0] += a.x*a.x; sq[mt][1] += a.y*a.y; sq[mt][2] += a.z*a.z; sq[mt][3] += a.w*a.w;
    }
  }
  #pragma unroll
  for (int mt = 0; mt < 2; ++mt)
    #pragma unroll
    for (int r2 = 0; r2 < 4; ++r2){
      float v1 = ss[mt][r2], v2 = sq[mt][r2];
      for (int d = 1; d < 16; d <<= 1){ v1 += __shfl_xor(v1, d, 64); v2 += __shfl_xor(v2, d, 64); }
      if (bL == 0){
        int cch = mt*16 + jj*4 + r2;
        sred[0][w][cch] = v1;
        sred[1][w][cch] = v2;
      }
    }
  __syncthreads();
  if (t < 64){
    const int cch = t & 31, j2 = t >> 5;
    float tot = sred[j2][0][cch] + sred[j2][1][cch] + sred[j2][2][cch] + sred[j2][3][cch];
    const int bid = (z*36 + blockIdx.y)*64 + blockIdx.x;
    ws[(j2 ? OFF_P3Q : OFF_P3S) + bid*32 + cch] = tot;
  }
  unsigned short* st = sa + w*4608;
  #pragma unroll
  for (int idx = 0; idx < 8; ++idx){
    if (idx >= nvalid) continue;
    #pragma unroll
    for (int mt = 0; mt < 2; ++mt){
      floatx4 a = acc[idx][mt];
      uint2 pk;
      pk.x = (unsigned int)f2bu(a.x) | ((unsigned int)f2bu(a.y) << 16);
      pk.y = (unsigned int)f2bu(a.z) | ((unsigned int)f2bu(a.w) << 16);
      *(uint2*)(st + idx*576 + bL*36 + mt*16 + jj*4) = pk;
    }
  }
  const int sb = L >> 2, q2 = L & 3;
  #pragma unroll
  for (int idx = 0; idx < 8; ++idx){
    if (idx >= nvalid) continue;
    const int wo = s0 + idx;
    uint4 v = *(const uint4*)(st + idx*576 + sb*36 + q2*8);
    *(uint4*)(x3 + ((size_t)(ho*55+wo)*1024 + b0 + sb)*32 + q2*8) = v;
  }
}

// ============ deconv4 (MFMA, banded A): x3 -> o4 (B,36,105) ============
// out[b][ho][wo] = sum_{r,wi,ci} A[wo][r,wi,ci]*act3[hi=ho-1+r][wi][b][ci], kw = 2*wi - wo
// wo-tile T: wo = 16T+m, wi = 8T+d (d<10); A-frag fw4[r][d] tile-independent.
__global__ __launch_bounds__(256) void k_dc4(const unsigned short* __restrict__ x3,
                                             const unsigned short* __restrict__ fw4,
                                             float* __restrict__ o4, const float* __restrict__ ws){
  const int t = threadIdx.x;
  const int w = t >> 6, L = t & 63;
  const int b0 = blockIdx.x*16;
  const int ho0 = blockIdx.y*3;
  __shared__ float a3s[32], c3s[32];
  __shared__ unsigned short fa4[30*512];     // [r*10+d][L*8]
  __shared__ float rowbuf[16*113];
  if (t < 32){ a3s[t] = ws[OFF_A3+t]; c3s[t] = ws[OFF_C3+t]; }
  for (int i = t; i < 1920; i += 256)
    *(uint4*)(fa4 + (size_t)i*8) = *(const uint4*)(fw4 + (size_t)i*8);
  __syncthreads();
  const int bL = L & 15, jj = (L>>4)&3, ci0 = jj*8;
  float an[8], cn[8];
  #pragma unroll
  for (int e = 0; e < 8; ++e){ an[e] = a3s[ci0+e]; cn[e] = c3s[ci0+e]; }
  floatx4 acc[2][3];
  #pragma unroll
  for (int i = 0; i < 2; ++i)
    #pragma unroll
    for (int h = 0; h < 3; ++h) acc[i][h] = (floatx4)0.f;
  #pragma unroll
  for (int ts = 0; ts < 2; ++ts){
    const int T = w + ts*4;
    if (T >= 7) continue;                    // only wave 3, ts=1
    const int dmax = (T == 6) ? 7 : 10;      // wi = 8T+d < 55
    #pragma unroll
    for (int e = 0; e < 5; ++e){             // hi = ho0-1+e
      const int hi = ho0 - 1 + e;
      if (hi < 0 || hi >= 36) continue;      // uniform
      for (int d = 0; d < dmax; ++d){
        const int wi = 8*T + d;
        uint4 v = *(const uint4*)(x3 + ((size_t)(hi*55 + wi)*1024 + b0 + bL)*32 + ci0);
        v.x = nrm2(v.x, an[0], cn[0], an[1], cn[1]);
        v.y = nrm2(v.y, an[2], cn[2], an[3], cn[3]);
        v.z = nrm2(v.z, an[4], cn[4], an[5], cn[5]);
        v.w = nrm2(v.w, an[6], cn[6], an[7], cn[7]);
        short8 bf = __builtin_bit_cast(short8, v);
        #pragma unroll
        for (int hl = 0; hl < 3; ++hl){
          const int r = e - hl;              // compile-time prune
          if (r < 0 || r > 2) continue;
          short8 af = *(const short8*)(fa4 + ((size_t)(r*10 + d)*64 + L)*8);
          acc[ts][hl] = mfma16(af, bf, acc[ts][hl]);
        }
      }
    }
  }
  #pragma unroll
  for (int hl = 0; hl < 3; ++hl){
    __syncthreads();
    #pragma unroll
    for (int ts = 0; ts < 2; ++ts){
      const int T = w + ts*4;
      if (T >= 7) continue;
      floatx4 a = acc[ts][hl];
      float vals[4] = {a.x, a.y, a.z, a.w};
      #pragma unroll
      for (int reg = 0; reg < 4; ++reg){
        const int wo = 16*T + jj*4 + reg;
        if (wo < 105) rowbuf[bL*113 + wo] = vals[reg];
      }
    }
    __syncthreads();
    const int ho = ho0 + hl;
    for (int i = t; i < 1680; i += 256){
      const int bb = i / 105, wo = i - bb*105;
      o4[(size_t)(b0 + bb)*3780 + ho*105 + wo] = rowbuf[bb*113 + wo];
    }
  }
}

// ============ node softmax / outputs ============
__global__ __launch_bounds__(256) void k_node(const float* __restrict__ o4, float* __restrict__ dout,
                                              float* __restrict__ ws){
  const int t = threadIdx.x;
  const int tg = blockIdx.x*256 + t;
  __shared__ float red[256];
  float lp = 0.f;
  {
    int b = tg / 30, n = tg - b*30;
    const float* p = o4 + (size_t)b*3780 + n*126;
    float l[6]; float mx = -1e30f;
    #pragma unroll
    for (int j = 0; j < 6; ++j){ l[j] = p[j]; mx = fmaxf(mx, l[j]); }
    float e[6]; float s = 0.f;
    #pragma unroll
    for (int j = 0; j < 6; ++j){ e[j] = expf(l[j] - mx); s += e[j]; }
    float inv = 1.f / s;
    int am = 0; float best = e[0];
    #pragma unroll
    for (int j = 1; j < 6; ++j){ if (e[j] > best){ best = e[j]; am = j; } }
    #pragma unroll
    for (int j = 0; j < 5; ++j) dout[OUT0 + (size_t)tg*5 + j] = e[j+1]*inv;
    dout[OUT3 + tg] = 1.f - e[0]*inv;
    #pragma unroll
    for (int j = 0; j < 5; ++j) dout[OUT6 + (size_t)tg*5 + j] = (am == j+1) ? 1.f : 0.f;
    dout[OUT8 + tg] = (am != 0) ? 1.f : 0.f;
    dout[OUT5 + tg] = (float)b;
    lp = logf(best*inv + 1e-7f);
  }
  red[t] = lp; __syncthreads();
  for (int off = 128; off > 0; off >>= 1){ if (t < off) red[t] += red[t+off]; __syncthreads(); }
  if (t == 0) atomicAdd(&ws[OFF_LP], red[0]);
}

// ============ edge softmax / outputs ============
__global__ __launch_bounds__(256) void k_edge(const float* __restrict__ o4, float* __restrict__ dout,
                                              float* __restrict__ ws){
  const int t = threadIdx.x;
  const int tg = blockIdx.x*256 + t;
  __shared__ float red[256];
  float lp = 0.f;
  {
    int b = tg / 435, k = tg - b*435;
    int i = 0, rem = k;
    while (rem >= 29 - i){ rem -= 29 - i; ++i; }
    int j = i + 1 + rem;
    const float* p = o4 + (size_t)b*3780 + i*126 + 6 + j*4;
    float l0 = p[0], l1 = p[1], l2 = p[2], l3 = p[3];
    float mx = fmaxf(fmaxf(l0, l1), fmaxf(l2, l3));
    float e0 = expf(l0-mx), e1 = expf(l1-mx), e2 = expf(l2-mx), e3 = expf(l3-mx);
    float inv = 1.f / (e0 + e1 + e2 + e3);
    float pr0 = e0*inv, pr1 = e1*inv, pr2 = e2*inv, pr3 = e3*inv;
    int am = 0; float best = pr0;
    if (pr1 > best){ best = pr1; am = 1; }
    if (pr2 > best){ best = pr2; am = 2; }
    if (pr3 > best){ best = pr3; am = 3; }
    size_t e1i = (size_t)b*870 + k, e2i = e1i + 435;
    dout[OUT2 + e1i*3 + 0] = pr1; dout[OUT2 + e1i*3 + 1] = pr2; dout[OUT2 + e1i*3 + 2] = pr3;
    dout[OUT2 + e2i*3 + 0] = pr1; dout[OUT2 + e2i*3 + 1] = pr2; dout[OUT2 + e2i*3 + 2] = pr3;
    dout[OUT4 + e1i] = 1.f - pr0;  dout[OUT4 + e2i] = 1.f - pr0;
    float h1 = (am == 1) ? 1.f : 0.f, h2 = (am == 2) ? 1.f : 0.f, h3 = (am == 3) ? 1.f : 0.f;
    dout[OUT7 + e1i*3 + 0] = h1; dout[OUT7 + e1i*3 + 1] = h2; dout[OUT7 + e1i*3 + 2] = h3;
    dout[OUT7 + e2i*3 + 0] = h1; dout[OUT7 + e2i*3 + 1] = h2; dout[OUT7 + e2i*3 + 2] = h3;
    dout[OUT9 + e1i] = (am != 0) ? 1.f : 0.f;  dout[OUT9 + e2i] = (am != 0) ? 1.f : 0.f;
    if (b == 0){
      dout[OUT1 + k]        = (float)i;
      dout[OUT1 + 435 + k]  = (float)j;
      dout[OUT1 + 870 + k]  = (float)j;
      dout[OUT1 + 1305 + k] = (float)i;
    }
    lp = logf(best + 1e-7f);
  }
  red[t] = lp; __syncthreads();
  for (int off = 128; off > 0; off >>= 1){ if (t < off) red[t] += red[t+off]; __syncthreads(); }
  if (t == 0) atomicAdd(&ws[OFF_LP], red[0]);
}

__global__ void k_lp_copy(float* __restrict__ dout, const float* __restrict__ ws){
  if (threadIdx.x == 0 && blockIdx.x == 0) dout[OUT10] = ws[OFF_LP];
}

extern "C" void kernel_launch(void* const* d_in, const int* in_sizes, int n_in,
                              void* d_out, int out_size, void* d_ws, size_t ws_size,
                              hipStream_t stream) {
  const float* Z  = (const float*)d_in[0];
  const float* W1 = (const float*)d_in[1];
  const float* W2 = (const float*)d_in[2];
  const float* W3 = (const float*)d_in[3];
  const float* W4 = (const float*)d_in[4];
  const float* g1 = (const float*)d_in[5];
  const float* b1 = (const float*)d_in[6];
  const float* g2 = (const float*)d_in[7];
  const float* b2 = (const float*)d_in[8];
  const float* g3 = (const float*)d_in[9];
  const float* b3 = (const float*)d_in[10];

  float* ws  = (float*)d_ws;
  char*  wsb = (char*)d_ws;
  unsigned short* fw2 = (unsigned short*)(wsb + FW2_BYTE);
  unsigned short* fw3 = (unsigned short*)(wsb + FW3_BYTE);
  unsigned short* fw4 = (unsigned short*)(wsb + FW4_BYTE);
  unsigned short* x2u = (unsigned short*)(wsb + X2_BYTE);
  unsigned short* x3u = (unsigned short*)(wsb + X3_BYTE);
  float*          o4  = (float*)(wsb + O4_BYTE);
  float* dout = (float*)d_out;
  (void)in_sizes; (void)n_in; (void)out_size; (void)ws_size;

  k_prep<<<dim3(9), dim3(256), 0, stream>>>(W2, W3, W4, fw2, fw3, fw4);
  k_dc1<<<dim3(1024), dim3(256), 0, stream>>>(Z, W1, ws);
  k_fin<<<dim3(64), dim3(256), 0, stream>>>(ws, g1, b1, OFF_P1S, OFF_P1Q, 1024, 64,
                                            1.f/243712.f, OFF_A1, OFF_C1, 0);
  k2<<<dim3(64, 36), dim3(256), 0, stream>>>(Z, W1, fw2, x2u, ws);
  k_fin<<<dim3(32), dim3(256), 0, stream>>>(ws, g2, b2, OFF_P2S, OFF_P2Q, 2304, 32,
                                            1.f/995328.f, OFF_A2, OFF_C2, 0);
  k3<<<dim3(64, 36, 2), dim3(256), 0, stream>>>(x2u, fw3, x3u, ws);
  k_fin<<<dim3(32), dim3(256), 0, stream>>>(ws, g3, b3, OFF_P3S, OFF_P3Q, 4608, 32,
                                            1.f/2027520.f, OFF_A3, OFF_C3, 1);
  k_dc4<<<dim3(64, 12), dim3(256), 0, stream>>>(x3u, fw4, o4, ws);
  k_node<<<dim3(120), dim3(256), 0, stream>>>(o4, dout, ws);
  k_edge<<<dim3(1740), dim3(256), 0, stream>>>(o4, dout, ws);
  k_lp_copy<<<dim3(1), dim3(64), 0, stream>>>(dout, ws);
}